// Round 3
// baseline (543.671 us; speedup 1.0000x reference)
//
#include <hip/hip_runtime.h>

typedef unsigned short u16;
typedef float fx4 __attribute__((ext_vector_type(4)));
typedef __bf16 bfx8 __attribute__((ext_vector_type(8)));

#define NSLOTS 4096
#define NEG_INF (-1e30f)
// H^-0.5 * log2(e): softmax runs in base-2 (v_exp_f32 is natively 2^x)
#define QSCALE 0.12751879523486166f

__device__ __forceinline__ u16 f2bf(float f) {
    union { float f; unsigned u; } v; v.f = f;
    unsigned u = v.u;
    unsigned r = (u + 0x7FFFu + ((u >> 16) & 1u)) >> 16;
    return (u16)r;
}
__device__ __forceinline__ float bf2f(u16 h) {
    union { unsigned u; float f; } v; v.u = ((unsigned)h) << 16; return v.f;
}
__device__ __forceinline__ void gll16(const void* g, void* l) {
    __builtin_amdgcn_global_load_lds((__attribute__((address_space(1))) void*)(g),
                                     (__attribute__((address_space(3))) void*)(l),
                                     16, 0, 0);
}

// -------- 64x64 transpose-convert tile: in (R,C) f32 -> out (C,R) bf16 --------
__device__ __forceinline__ void transpose_body(u16 (*t)[72],
                                               const float* __restrict__ ih,
                                               u16* __restrict__ oh, int R, int C,
                                               int r0, int c0) {
    int tid = threadIdx.x;
    int rr = tid >> 4, c4 = tid & 15;
#pragma unroll
    for (int i = 0; i < 4; ++i) {
        int r = rr + i * 16;
        float4 v = *(const float4*)(ih + (size_t)(r0 + r) * C + c0 + c4 * 4);
        t[c4 * 4 + 0][r] = f2bf(v.x);
        t[c4 * 4 + 1][r] = f2bf(v.y);
        t[c4 * 4 + 2][r] = f2bf(v.z);
        t[c4 * 4 + 3][r] = f2bf(v.w);
    }
    __syncthreads();
    int rr2 = tid >> 3, c8 = tid & 7;
#pragma unroll
    for (int i = 0; i < 2; ++i) {
        int r = rr2 + i * 32;
        *(uint4*)(oh + (size_t)(c0 + r) * R + r0 + c8 * 8) = *(uint4*)&t[r][c8 * 8];
    }
}

// ---------------- fused prep: cache copy + x cvt + weight transposes ----------------
// blocks [0,4096):      cache d2d copy (k_cache, v_cache -> d_out, contiguous)
// blocks [4096,8192):   x f32 -> bf16
// blocks [8192,14336):  wq/wk/wv per-head transpose (D,H)->(H,D) bf16
// blocks [14336,18432): wo transpose (4096,4096) -> bf16
__global__ __launch_bounds__(256) void prep(
    const float* __restrict__ x, const float* __restrict__ wq,
    const float* __restrict__ wk, const float* __restrict__ wv,
    const float* __restrict__ wo, const float* __restrict__ kc,
    const float* __restrict__ vc, u16* __restrict__ x_bf,
    u16* __restrict__ wqkvT, u16* __restrict__ woT, float* __restrict__ cache_out) {
    __shared__ __align__(16) u16 t[64][72];
    int id = blockIdx.x;
    int tid = threadIdx.x;
    if (id < 4096) {
        // 2.097M float4 total; 512 per block; kc blocks [0,2048), vc [2048,4096)
        int f4i = id * 512 + tid * 2;
        const float4* src = (id < 2048) ? (const float4*)kc + f4i
                                        : (const float4*)vc + (f4i - 1048576);
        float4 a = src[0], b = src[1];
        float4* dst = (float4*)cache_out + f4i;
        dst[0] = a;
        dst[1] = b;
    } else if (id < 8192) {
        int i = ((id - 4096) * 256 + tid) * 8;
        float4 a = *(const float4*)(x + i);
        float4 b = *(const float4*)(x + i + 4);
        u16 tmp[8] = {f2bf(a.x), f2bf(a.y), f2bf(a.z), f2bf(a.w),
                      f2bf(b.x), f2bf(b.y), f2bf(b.z), f2bf(b.w)};
        *(uint4*)(x_bf + i) = *(uint4*)tmp;
    } else if (id < 14336) {
        int id3 = id - 8192;
        int z = id3 >> 7;          // head 0..47
        int rem = id3 & 127;
        int by = rem >> 1, bx = rem & 1;
        const float* in = (z < 32) ? wq + (size_t)z * 524288
                                   : (z < 40) ? wk + (size_t)(z - 32) * 524288
                                              : wv + (size_t)(z - 40) * 524288;
        transpose_body(t, in, wqkvT + (size_t)z * 524288, 4096, 128, by * 64,
                       bx * 64);
    } else {
        int id4 = id - 14336;
        int bx = id4 & 63, by = id4 >> 6;
        transpose_body(t, wo, woT, 4096, 4096, by * 64, bx * 64);
    }
}

// ---------------- bf16 GEMM, both operands K-contiguous (B^T) ----------------
template <int OUTF32>
__global__ __launch_bounds__(256) void gemm_bt(const u16* __restrict__ A,
                                               const u16* __restrict__ Bt,
                                               void* __restrict__ Cv,
                                               int M, int N, int Kd) {
    __shared__ __align__(16) u16 As[128 * 64];
    __shared__ __align__(16) u16 Bs[128 * 64];
    const int tid = threadIdx.x;
    const int lane = tid & 63;
    const int wave = tid >> 6;
    const int wm = (wave >> 1) * 64;
    const int wn = (wave & 1) * 64;
    const int m0 = blockIdx.y * 128;
    const int n0 = blockIdx.x * 128;
    const int quad = lane >> 4;
    const int l15 = lane & 15;
    const int srow = lane >> 3;
    const int sc8 = (lane & 7) ^ srow;

    fx4 zero = {0.f, 0.f, 0.f, 0.f};
    fx4 acc[4][4];
#pragma unroll
    for (int i = 0; i < 4; ++i)
#pragma unroll
        for (int j = 0; j < 4; ++j) acc[i][j] = zero;

    for (int k0 = 0; k0 < Kd; k0 += 64) {
        __syncthreads();
#pragma unroll
        for (int i = 0; i < 4; ++i) {
            int c = wave * 4 + i;
            gll16(A + (size_t)(m0 + c * 8 + srow) * Kd + (k0 + sc8 * 8), &As[c * 512]);
            gll16(Bt + (size_t)(n0 + c * 8 + srow) * Kd + (k0 + sc8 * 8), &Bs[c * 512]);
        }
        __syncthreads();
#pragma unroll
        for (int ks = 0; ks < 2; ++ks) {
            bfx8 af[4], bf[4];
#pragma unroll
            for (int t = 0; t < 4; ++t) {
                int row = wm + t * 16 + l15;
                int r7 = row & 7;
                int k8 = (ks * 4 + quad) ^ r7;
                af[t] = *(const bfx8*)&As[(row >> 3) * 512 + r7 * 64 + k8 * 8];
                int rowb = wn + t * 16 + l15;
                int r7b = rowb & 7;
                int k8b = (ks * 4 + quad) ^ r7b;
                bf[t] = *(const bfx8*)&Bs[(rowb >> 3) * 512 + r7b * 64 + k8b * 8];
            }
#pragma unroll
            for (int tm = 0; tm < 4; ++tm)
#pragma unroll
                for (int tn = 0; tn < 4; ++tn)
                    acc[tm][tn] = __builtin_amdgcn_mfma_f32_16x16x32_bf16(
                        af[tm], bf[tn], acc[tm][tn], 0, 0, 0);
        }
    }
#pragma unroll
    for (int tm = 0; tm < 4; ++tm)
#pragma unroll
        for (int tn = 0; tn < 4; ++tn) {
            int col = n0 + wn + tn * 16 + l15;
#pragma unroll
            for (int r = 0; r < 4; ++r) {
                int row = m0 + wm + tm * 16 + quad * 4 + r;
                if (OUTF32)
                    ((float*)Cv)[(size_t)row * N + col] = acc[tm][tn][r];
                else
                    ((u16*)Cv)[(size_t)row * N + col] = f2bf(acc[tm][tn][r]);
            }
        }
}

// ---------------- fused RoPE + cache scatter + V transpose ----------------
// blocks [0,24576):       rope: m = id/12, j-range = (id%12)*256
// blocks [24576,25088):   V transpose qkv -> vt (h, t) per (b,kh)
__global__ __launch_bounds__(256) void rope_tv(
    const u16* __restrict__ qkv, const int* __restrict__ positions,
    const int* __restrict__ wi, u16* __restrict__ qb, u16* __restrict__ kb,
    float* __restrict__ kcache, float* __restrict__ vcache, u16* __restrict__ vt) {
    __shared__ __align__(16) u16 Ts[64 * 64];
    int id = blockIdx.x;
    int tid = threadIdx.x;
    if (id < 24576) {
        int m = id / 12;
        int j2 = (id % 12) * 256 + tid;  // 0..3071
        int head = j2 >> 6;
        int hp = (j2 & 63) * 2;  // even h; pair never straddles half=64
        int b = m >> 10, t = m & 1023;
        const u16* row = qkv + (size_t)m * 6144 + head * 128;
        unsigned sv = *(const unsigned*)(row + hp);
        float v0 = bf2f((u16)sv), v1 = bf2f((u16)(sv >> 16));
        if (head < 40) {
            int i = hp & 63;
            float p = (float)positions[m];
            float ang0 = p * __expf(-0.20503693f * (float)i);  // theta^(-i/64)
            float ang1 = ang0 * 0.81461709f;                   // * theta^(-1/64)
            float c0, s0, c1, s1;
            __sincosf(ang0, &s0, &c0);
            __sincosf(ang1, &s1, &c1);
            unsigned ov = *(const unsigned*)(row + (hp ^ 64));
            float w0 = bf2f((u16)ov), w1 = bf2f((u16)(ov >> 16));
            float o0, o1;
            if (hp < 64) { o0 = v0 * c0 - w0 * s0; o1 = v1 * c1 - w1 * s1; }
            else         { o0 = v0 * c0 + w0 * s0; o1 = v1 * c1 + w1 * s1; }
            if (head < 32) {
                o0 *= QSCALE; o1 *= QSCALE;
                u16 t2[2] = {f2bf(o0), f2bf(o1)};
                *(unsigned*)(qb + ((size_t)(b * 32 + head) * 1024 + t) * 128 + hp) =
                    *(unsigned*)t2;
            } else {
                int kh = head - 32;
                u16 t2[2] = {f2bf(o0), f2bf(o1)};
                *(unsigned*)(kb + ((size_t)(b * 8 + kh) * 1024 + t) * 128 + hp) =
                    *(unsigned*)t2;
                float2 f2 = {o0, o1};
                *(float2*)(kcache + ((size_t)kh * NSLOTS + wi[m]) * 128 + hp) = f2;
            }
        } else {
            int kh = head - 40;
            float2 f2 = {v0, v1};
            *(float2*)(vcache + ((size_t)kh * NSLOTS + wi[m]) * 128 + hp) = f2;
        }
    } else {
        int idx = id - 24576;
        int tt = idx & 15;          // t-tile
        int hh = (idx >> 4) & 1;    // h-tile
        int bkh = idx >> 5;         // b*8+kh
        int bq = bkh >> 3, kh = bkh & 7;
        const u16* src =
            qkv + (size_t)(bq * 1024 + tt * 64) * 6144 + 5120 + kh * 128 + hh * 64;
        {
            int r = tid >> 3, c8 = tid & 7;
#pragma unroll
            for (int i = 0; i < 2; ++i) {
                int rr = r + i * 32;
                *(uint4*)&Ts[rr * 64 + ((c8 ^ (rr & 7)) * 8)] =
                    *(const uint4*)(src + (size_t)rr * 6144 + c8 * 8);
            }
        }
        __syncthreads();
        int h = tid & 63, t8 = tid >> 6;
        int h8 = h >> 3, h7 = h & 7;
        u16* dst =
            vt + (size_t)bkh * 131072 + (size_t)(hh * 64 + h) * 1024 + tt * 64;
#pragma unroll
        for (int i = 0; i < 2; ++i) {
            int tb = t8 + i * 4;
            u16 tmp[8];
#pragma unroll
            for (int j = 0; j < 8; ++j)
                tmp[j] = Ts[(tb * 8 + j) * 64 + ((h8 ^ j) * 8 + h7)];
            *(uint4*)(dst + tb * 8) = *(uint4*)tmp;
        }
    }
}

// ---------------- causal flash attention ----------------
// grid (qt=16, n=32, b=2), block 256 (4 waves x 16 query rows)
__global__ __launch_bounds__(256) void flash_attn(const u16* __restrict__ qb,
                                                  const u16* __restrict__ kb,
                                                  const u16* __restrict__ vt,
                                                  u16* __restrict__ attn) {
    const int qt = blockIdx.x;
    const int n = blockIdx.y;
    const int b = blockIdx.z;
    const int kh = n >> 2;
    const int tid = threadIdx.x;
    const int lane = tid & 63;
    const int wave = tid >> 6;
    const int quad = lane >> 4;
    const int l15 = lane & 15;

    __shared__ __align__(16) u16 Ks[64 * 128];    // (key, h), h8 ^= key&7
    __shared__ __align__(16) u16 Vs[128 * 64];    // (h, key), k8 ^= h&7
    __shared__ __align__(16) u16 Ps[4][16 * 72];  // per-wave P, +8 pad

    const u16* qbase =
        qb + ((size_t)(b * 32 + n) * 1024 + qt * 64 + wave * 16 + l15) * 128;
    bfx8 qf[4];
#pragma unroll
    for (int ks = 0; ks < 4; ++ks)
        qf[ks] = *(const bfx8*)(qbase + ks * 32 + quad * 8);

    const u16* kbase = kb + (size_t)(b * 8 + kh) * 131072;
    const u16* vbase = vt + (size_t)(b * 8 + kh) * 131072;

    const int kl = wave * 4 + (lane >> 4);
    const int kh8 = (lane & 15) ^ (kl & 7);
    const int hl = wave * 8 + (lane >> 3);
    const int vk8 = (lane & 7) ^ (hl & 7);

    fx4 zero = {0.f, 0.f, 0.f, 0.f};
    fx4 o[8];
#pragma unroll
    for (int i = 0; i < 8; ++i) o[i] = zero;
    float mrow[4], lrow[4];
#pragma unroll
    for (int r = 0; r < 4; ++r) { mrow[r] = NEG_INF; lrow[r] = 0.f; }

    for (int kt = 0; kt <= qt; ++kt) {
        __syncthreads();
        const u16* ksrc = kbase + (size_t)kt * 64 * 128;
        const u16* vsrc = vbase + kt * 64;
#pragma unroll
        for (int i = 0; i < 4; ++i)
            gll16(ksrc + (size_t)(i * 16 + kl) * 128 + kh8 * 8,
                  &Ks[(i * 16 + wave * 4) * 128]);
#pragma unroll
        for (int i = 0; i < 4; ++i)
            gll16(vsrc + (size_t)(i * 32 + hl) * 1024 + vk8 * 8,
                  &Vs[(i * 32 + wave * 8) * 64]);
        __syncthreads();

        fx4 sAcc[4];
#pragma unroll
        for (int t = 0; t < 4; ++t) sAcc[t] = zero;
#pragma unroll
        for (int ks = 0; ks < 4; ++ks)
#pragma unroll
            for (int tn = 0; tn < 4; ++tn) {
                int key = tn * 16 + l15;
                bfx8 kf =
                    *(const bfx8*)&Ks[key * 128 + (((ks * 4 + quad) ^ (key & 7)) * 8)];
                sAcc[tn] = __builtin_amdgcn_mfma_f32_16x16x32_bf16(qf[ks], kf,
                                                                   sAcc[tn], 0, 0, 0);
            }
        if (kt == qt) {
#pragma unroll
            for (int tn = 0; tn < 4; ++tn)
#pragma unroll
                for (int r = 0; r < 4; ++r) {
                    int qrow = wave * 16 + quad * 4 + r;
                    int krow = tn * 16 + l15;
                    if (krow > qrow) sAcc[tn][r] = NEG_INF;
                }
        }
        float alpha[4];
#pragma unroll
        for (int r = 0; r < 4; ++r) {
            float mx = fmaxf(fmaxf(sAcc[0][r], sAcc[1][r]),
                             fmaxf(sAcc[2][r], sAcc[3][r]));
#pragma unroll
            for (int d = 1; d < 16; d <<= 1) mx = fmaxf(mx, __shfl_xor(mx, d));
            float mnew = fmaxf(mrow[r], mx);
            alpha[r] = exp2f(mrow[r] - mnew);
            mrow[r] = mnew;
            float rs = 0.f;
#pragma unroll
            for (int tn = 0; tn < 4; ++tn) {
                float p = exp2f(sAcc[tn][r] - mnew);
                sAcc[tn][r] = p;
                rs += p;
            }
#pragma unroll
            for (int d = 1; d < 16; d <<= 1) rs += __shfl_xor(rs, d);
            lrow[r] = lrow[r] * alpha[r] + rs;
        }
#pragma unroll
        for (int tn = 0; tn < 4; ++tn)
#pragma unroll
            for (int r = 0; r < 4; ++r)
                Ps[wave][(quad * 4 + r) * 72 + tn * 16 + l15] = f2bf(sAcc[tn][r]);
#pragma unroll
        for (int ht = 0; ht < 8; ++ht)
#pragma unroll
            for (int r = 0; r < 4; ++r) o[ht][r] *= alpha[r];
#pragma unroll
        for (int ks2 = 0; ks2 < 2; ++ks2) {
            bfx8 pf = *(const bfx8*)&Ps[wave][l15 * 72 + ks2 * 32 + quad * 8];
#pragma unroll
            for (int ht = 0; ht < 8; ++ht) {
                int h = ht * 16 + l15;
                bfx8 vf =
                    *(const bfx8*)&Vs[h * 64 + (((ks2 * 4 + quad) ^ (h & 7)) * 8)];
                o[ht] = __builtin_amdgcn_mfma_f32_16x16x32_bf16(pf, vf, o[ht], 0, 0, 0);
            }
        }
    }
    float inv_l[4];
#pragma unroll
    for (int r = 0; r < 4; ++r) inv_l[r] = 1.f / lrow[r];
#pragma unroll
    for (int ht = 0; ht < 8; ++ht)
#pragma unroll
        for (int r = 0; r < 4; ++r) {
            int t = qt * 64 + wave * 16 + quad * 4 + r;
            int col = n * 128 + ht * 16 + l15;
            attn[((size_t)(b * 1024 + t)) * 4096 + col] = f2bf(o[ht][r] * inv_l[r]);
        }
}

extern "C" void kernel_launch(void* const* d_in, const int* in_sizes, int n_in,
                              void* d_out, int out_size, void* d_ws, size_t ws_size,
                              hipStream_t stream) {
    const float* x = (const float*)d_in[0];
    const int* pos = (const int*)d_in[1];
    const float* wq = (const float*)d_in[2];
    const float* wk = (const float*)d_in[3];
    const float* wv = (const float*)d_in[4];
    const float* wo = (const float*)d_in[5];
    const float* kc = (const float*)d_in[6];
    const float* vc = (const float*)d_in[7];
    const int* wi = (const int*)d_in[8];

    float* kc_out = (float*)d_out;   // (8, 4096, 128)
    float* vc_out = kc_out + 4194304;
    float* o_out = vc_out + 4194304; // (2, 1024, 4096)

    u16* wsp = (u16*)d_ws;
    u16* x_bf  = wsp;                // (2048, 4096)
    u16* wqkvT = x_bf + 8388608;     // (6144, 4096) heads x (H, D)
    u16* woT   = wqkvT + 25165824;   // (4096, 4096)
    u16* qkv   = woT + 16777216;     // (2048, 6144)
    u16* qbuf  = qkv + 12582912;     // (2, 32, 1024, 128)
    u16* kbuf  = qbuf + 8388608;     // (2, 8, 1024, 128)
    u16* vtb   = kbuf + 2097152;     // (2, 8, 128, 1024)
    u16* attn  = vtb + 2097152;      // (2048, 4096)

    prep<<<18432, 256, 0, stream>>>(x, wq, wk, wv, wo, kc, vc, x_bf, wqkvT, woT,
                                    kc_out);
    gemm_bt<0><<<dim3(48, 16), 256, 0, stream>>>(x_bf, wqkvT, qkv, 2048, 6144, 4096);
    rope_tv<<<25088, 256, 0, stream>>>(qkv, pos, wi, qbuf, kbuf, kc_out, vc_out, vtb);
    flash_attn<<<dim3(16, 32, 2), 256, 0, stream>>>(qbuf, kbuf, vtb, attn);
    gemm_bt<1><<<dim3(32, 16), 256, 0, stream>>>(attn, woT, o_out, 2048, 4096, 4096);
}

// Round 4
// 515.982 us; speedup vs baseline: 1.0537x; 1.0537x over previous
//
#include <hip/hip_runtime.h>

typedef unsigned short u16;
typedef float fx4 __attribute__((ext_vector_type(4)));
typedef __bf16 bfx8 __attribute__((ext_vector_type(8)));

#define NSLOTS 4096
#define NEG_INF (-1e30f)
// H^-0.5 * log2(e): softmax runs in base-2 (v_exp_f32 is natively 2^x)
#define QSCALE 0.12751879523486166f

__device__ __forceinline__ u16 f2bf(float f) {
    union { float f; unsigned u; } v; v.f = f;
    unsigned u = v.u;
    unsigned r = (u + 0x7FFFu + ((u >> 16) & 1u)) >> 16;
    return (u16)r;
}
__device__ __forceinline__ float bf2f(u16 h) {
    union { unsigned u; float f; } v; v.u = ((unsigned)h) << 16; return v.f;
}
__device__ __forceinline__ void gll16(const void* g, void* l) {
    __builtin_amdgcn_global_load_lds((__attribute__((address_space(1))) void*)(g),
                                     (__attribute__((address_space(3))) void*)(l),
                                     16, 0, 0);
}

// -------- 64x64 transpose-convert tile: in (R,C) f32 -> out (C,R) bf16 --------
// LDS layout: element (a=out col, b=in row) at t[a*72 + ((b>>3 ^ (a&7))<<3) + (b&7)]
// XOR-granule swizzle -> conflict-light writes, 16B-aligned conflict-light reads.
__device__ __forceinline__ void transpose_body(u16* __restrict__ t,
                                               const float* __restrict__ ih,
                                               u16* __restrict__ oh, int R, int C,
                                               int r0, int c0) {
    int tid = threadIdx.x;
    int rr = tid >> 4, c4 = tid & 15;
#pragma unroll
    for (int i = 0; i < 4; ++i) {
        int b = rr + i * 16;
        float4 v = *(const float4*)(ih + (size_t)(r0 + b) * C + c0 + c4 * 4);
        u16 vals[4] = {f2bf(v.x), f2bf(v.y), f2bf(v.z), f2bf(v.w)};
#pragma unroll
        for (int j = 0; j < 4; ++j) {
            int a = c4 * 4 + j;
            t[a * 72 + (((b >> 3) ^ (a & 7)) << 3) + (b & 7)] = vals[j];
        }
    }
    __syncthreads();
    int rr2 = tid >> 3, c8 = tid & 7;
#pragma unroll
    for (int i = 0; i < 2; ++i) {
        int a = rr2 + i * 32;
        *(uint4*)(oh + (size_t)(c0 + a) * R + r0 + c8 * 8) =
            *(uint4*)&t[a * 72 + ((c8 ^ (a & 7)) << 3)];
    }
}

// ---------------- fused prep: cache copy + x cvt + weight transposes ----------------
// blocks [0,4096):      cache d2d copy (k_cache, v_cache -> d_out, contiguous)
// blocks [4096,8192):   x f32 -> bf16
// blocks [8192,14336):  wq/wk/wv per-head transpose (D,H)->(H,D) bf16
// blocks [14336,18432): wo transpose (4096,4096) -> bf16
__global__ __launch_bounds__(256) void prep(
    const float* __restrict__ x, const float* __restrict__ wq,
    const float* __restrict__ wk, const float* __restrict__ wv,
    const float* __restrict__ wo, const float* __restrict__ kc,
    const float* __restrict__ vc, u16* __restrict__ x_bf,
    u16* __restrict__ wqkvT, u16* __restrict__ woT, float* __restrict__ cache_out) {
    __shared__ __align__(16) u16 t[64 * 72];
    int id = blockIdx.x;
    int tid = threadIdx.x;
    if (id < 4096) {
        // lane-contiguous float4: each wave touches one 1KB segment per access
        int f4i = id * 512 + tid;
        const float4* src = (id < 2048) ? (const float4*)kc + f4i
                                        : (const float4*)vc + (f4i - 1048576);
        float4 a = src[0], b = src[256];
        float4* dst = (float4*)cache_out + f4i;
        dst[0] = a;
        dst[256] = b;
    } else if (id < 8192) {
        int i = ((id - 4096) * 256 + tid) * 8;
        float4 a = *(const float4*)(x + i);
        float4 b = *(const float4*)(x + i + 4);
        u16 tmp[8] = {f2bf(a.x), f2bf(a.y), f2bf(a.z), f2bf(a.w),
                      f2bf(b.x), f2bf(b.y), f2bf(b.z), f2bf(b.w)};
        *(uint4*)(x_bf + i) = *(uint4*)tmp;
    } else if (id < 14336) {
        int id3 = id - 8192;
        int z = id3 >> 7;  // head 0..47
        int rem = id3 & 127;
        int by = rem >> 1, bx = rem & 1;
        const float* in = (z < 32) ? wq + (size_t)z * 524288
                                   : (z < 40) ? wk + (size_t)(z - 32) * 524288
                                              : wv + (size_t)(z - 40) * 524288;
        transpose_body(t, in, wqkvT + (size_t)z * 524288, 4096, 128, by * 64,
                       bx * 64);
    } else {
        int id4 = id - 14336;
        int bx = id4 & 63, by = id4 >> 6;
        transpose_body(t, wo, woT, 4096, 4096, by * 64, bx * 64);
    }
}

// ---------------- bf16 GEMM core, both operands K-contiguous (B^T) ----------------
template <int OUTF32>
__device__ __forceinline__ void gemm_core(const u16* __restrict__ A,
                                          const u16* __restrict__ Bt,
                                          void* __restrict__ Cv,
                                          int M, int N, int Kd) {
    __shared__ __align__(16) u16 As[128 * 64];
    __shared__ __align__(16) u16 Bs[128 * 64];
    const int tid = threadIdx.x;
    const int lane = tid & 63;
    const int wave = tid >> 6;
    const int wm = (wave >> 1) * 64;
    const int wn = (wave & 1) * 64;
    const int m0 = blockIdx.y * 128;
    const int n0 = blockIdx.x * 128;
    const int quad = lane >> 4;
    const int l15 = lane & 15;
    const int srow = lane >> 3;
    const int sc8 = (lane & 7) ^ srow;

    fx4 zero = {0.f, 0.f, 0.f, 0.f};
    fx4 acc[4][4];
#pragma unroll
    for (int i = 0; i < 4; ++i)
#pragma unroll
        for (int j = 0; j < 4; ++j) acc[i][j] = zero;

    for (int k0 = 0; k0 < Kd; k0 += 64) {
        __syncthreads();
#pragma unroll
        for (int i = 0; i < 4; ++i) {
            int c = wave * 4 + i;
            gll16(A + (size_t)(m0 + c * 8 + srow) * Kd + (k0 + sc8 * 8), &As[c * 512]);
            gll16(Bt + (size_t)(n0 + c * 8 + srow) * Kd + (k0 + sc8 * 8), &Bs[c * 512]);
        }
        __syncthreads();
#pragma unroll
        for (int ks = 0; ks < 2; ++ks) {
            bfx8 af[4], bf[4];
#pragma unroll
            for (int t = 0; t < 4; ++t) {
                int row = wm + t * 16 + l15;
                int r7 = row & 7;
                int k8 = (ks * 4 + quad) ^ r7;
                af[t] = *(const bfx8*)&As[(row >> 3) * 512 + r7 * 64 + k8 * 8];
                int rowb = wn + t * 16 + l15;
                int r7b = rowb & 7;
                int k8b = (ks * 4 + quad) ^ r7b;
                bf[t] = *(const bfx8*)&Bs[(rowb >> 3) * 512 + r7b * 64 + k8b * 8];
            }
#pragma unroll
            for (int tm = 0; tm < 4; ++tm)
#pragma unroll
                for (int tn = 0; tn < 4; ++tn)
                    acc[tm][tn] = __builtin_amdgcn_mfma_f32_16x16x32_bf16(
                        af[tm], bf[tn], acc[tm][tn], 0, 0, 0);
        }
    }
#pragma unroll
    for (int tm = 0; tm < 4; ++tm)
#pragma unroll
        for (int tn = 0; tn < 4; ++tn) {
            int col = n0 + wn + tn * 16 + l15;
#pragma unroll
            for (int r = 0; r < 4; ++r) {
                int row = m0 + wm + tm * 16 + quad * 4 + r;
                if (OUTF32)
                    ((float*)Cv)[(size_t)row * N + col] = acc[tm][tn][r];
                else
                    ((u16*)Cv)[(size_t)row * N + col] = f2bf(acc[tm][tn][r]);
            }
        }
}

// distinct names for profiling attribution
__global__ __launch_bounds__(256) void gemm_qkv(const u16* __restrict__ A,
                                                const u16* __restrict__ Bt,
                                                u16* __restrict__ C, int M, int N,
                                                int Kd) {
    gemm_core<0>(A, Bt, C, M, N, Kd);
}
__global__ __launch_bounds__(256) void gemm_out(const u16* __restrict__ A,
                                                const u16* __restrict__ Bt,
                                                float* __restrict__ C, int M, int N,
                                                int Kd) {
    gemm_core<1>(A, Bt, C, M, N, Kd);
}

// ---------------- fused RoPE + cache scatter + V transpose ----------------
// blocks [0,24576):       rope: m = id/12, j-range = (id%12)*256
// blocks [24576,25088):   V transpose qkv -> vt (h, t) per (b,kh)
__global__ __launch_bounds__(256) void rope_tv(
    const u16* __restrict__ qkv, const int* __restrict__ positions,
    const int* __restrict__ wi, u16* __restrict__ qb, u16* __restrict__ kb,
    float* __restrict__ kcache, float* __restrict__ vcache, u16* __restrict__ vt) {
    __shared__ __align__(16) u16 Ts[64 * 64];
    int id = blockIdx.x;
    int tid = threadIdx.x;
    if (id < 24576) {
        int m = id / 12;
        int j2 = (id % 12) * 256 + tid;  // 0..3071
        int head = j2 >> 6;
        int hp = (j2 & 63) * 2;  // even h; pair never straddles half=64
        int b = m >> 10, t = m & 1023;
        const u16* row = qkv + (size_t)m * 6144 + head * 128;
        unsigned sv = *(const unsigned*)(row + hp);
        float v0 = bf2f((u16)sv), v1 = bf2f((u16)(sv >> 16));
        if (head < 40) {
            int i = hp & 63;
            float p = (float)positions[m];
            float ang0 = p * __expf(-0.20503693f * (float)i);  // theta^(-i/64)
            float ang1 = ang0 * 0.81461709f;                   // * theta^(-1/64)
            float c0, s0, c1, s1;
            __sincosf(ang0, &s0, &c0);
            __sincosf(ang1, &s1, &c1);
            unsigned ov = *(const unsigned*)(row + (hp ^ 64));
            float w0 = bf2f((u16)ov), w1 = bf2f((u16)(ov >> 16));
            float o0, o1;
            if (hp < 64) { o0 = v0 * c0 - w0 * s0; o1 = v1 * c1 - w1 * s1; }
            else         { o0 = v0 * c0 + w0 * s0; o1 = v1 * c1 + w1 * s1; }
            if (head < 32) {
                o0 *= QSCALE; o1 *= QSCALE;
                u16 t2[2] = {f2bf(o0), f2bf(o1)};
                *(unsigned*)(qb + ((size_t)(b * 32 + head) * 1024 + t) * 128 + hp) =
                    *(unsigned*)t2;
            } else {
                int kh = head - 32;
                u16 t2[2] = {f2bf(o0), f2bf(o1)};
                *(unsigned*)(kb + ((size_t)(b * 8 + kh) * 1024 + t) * 128 + hp) =
                    *(unsigned*)t2;
                float2 f2 = {o0, o1};
                *(float2*)(kcache + ((size_t)kh * NSLOTS + wi[m]) * 128 + hp) = f2;
            }
        } else {
            int kh = head - 40;
            float2 f2 = {v0, v1};
            *(float2*)(vcache + ((size_t)kh * NSLOTS + wi[m]) * 128 + hp) = f2;
        }
    } else {
        int idx = id - 24576;
        int tt = idx & 15;        // t-tile
        int hh = (idx >> 4) & 1;  // h-tile
        int bkh = idx >> 5;       // b*8+kh
        int bq = bkh >> 3, kh = bkh & 7;
        const u16* src =
            qkv + (size_t)(bq * 1024 + tt * 64) * 6144 + 5120 + kh * 128 + hh * 64;
        {
            int r = tid >> 3, c8 = tid & 7;
#pragma unroll
            for (int i = 0; i < 2; ++i) {
                int rr = r + i * 32;
                *(uint4*)&Ts[rr * 64 + ((c8 ^ (rr & 7)) * 8)] =
                    *(const uint4*)(src + (size_t)rr * 6144 + c8 * 8);
            }
        }
        __syncthreads();
        int h = tid & 63, t8 = tid >> 6;
        int h8 = h >> 3, h7 = h & 7;
        u16* dst =
            vt + (size_t)bkh * 131072 + (size_t)(hh * 64 + h) * 1024 + tt * 64;
#pragma unroll
        for (int i = 0; i < 2; ++i) {
            int tb = t8 + i * 4;
            u16 tmp[8];
#pragma unroll
            for (int j = 0; j < 8; ++j)
                tmp[j] = Ts[(tb * 8 + j) * 64 + ((h8 ^ j) * 8 + h7)];
            *(uint4*)(dst + tb * 8) = *(uint4*)tmp;
        }
    }
}

// ---------------- causal flash attention, balanced ----------------
// grid (p=8, n=32, b=2): block p handles q-tiles {p, 15-p} -> 17 K-iters each.
__global__ __launch_bounds__(256) void flash_attn(const u16* __restrict__ qb,
                                                  const u16* __restrict__ kb,
                                                  const u16* __restrict__ vt,
                                                  u16* __restrict__ attn) {
    const int p = blockIdx.x;
    const int n = blockIdx.y;
    const int b = blockIdx.z;
    const int kh = n >> 2;
    const int tid = threadIdx.x;
    const int lane = tid & 63;
    const int wave = tid >> 6;
    const int quad = lane >> 4;
    const int l15 = lane & 15;

    __shared__ __align__(16) u16 Ks[64 * 128];    // (key, h), h8 ^= key&7
    __shared__ __align__(16) u16 Vs[128 * 64];    // (h, key), k8 ^= h&7
    __shared__ __align__(16) u16 Ps[4][16 * 72];  // per-wave P, +8 pad

    const u16* kbase = kb + (size_t)(b * 8 + kh) * 131072;
    const u16* vbase = vt + (size_t)(b * 8 + kh) * 131072;

    const int kl = wave * 4 + (lane >> 4);
    const int kh8 = (lane & 15) ^ (kl & 7);
    const int hl = wave * 8 + (lane >> 3);
    const int vk8 = (lane & 7) ^ (hl & 7);

    fx4 zero = {0.f, 0.f, 0.f, 0.f};

    for (int ph = 0; ph < 2; ++ph) {
        const int qt = ph ? (15 - p) : p;
        const u16* qbase =
            qb + ((size_t)(b * 32 + n) * 1024 + qt * 64 + wave * 16 + l15) * 128;
        bfx8 qf[4];
#pragma unroll
        for (int ks = 0; ks < 4; ++ks)
            qf[ks] = *(const bfx8*)(qbase + ks * 32 + quad * 8);

        fx4 o[8];
#pragma unroll
        for (int i = 0; i < 8; ++i) o[i] = zero;
        float mrow[4], lrow[4];  // lrow is per-lane partial (reduced in epilogue)
#pragma unroll
        for (int r = 0; r < 4; ++r) { mrow[r] = NEG_INF; lrow[r] = 0.f; }

        for (int kt = 0; kt <= qt; ++kt) {
            __syncthreads();  // Ks/Vs free (previous PV done, all waves)
            const u16* ksrc = kbase + (size_t)kt * 64 * 128;
            const u16* vsrc = vbase + kt * 64;
#pragma unroll
            for (int i = 0; i < 4; ++i)
                gll16(ksrc + (size_t)(i * 16 + kl) * 128 + kh8 * 8,
                      &Ks[(i * 16 + wave * 4) * 128]);
#pragma unroll
            for (int i = 0; i < 4; ++i)
                gll16(vsrc + (size_t)(i * 32 + hl) * 1024 + vk8 * 8,
                      &Vs[(i * 32 + wave * 8) * 64]);
            __syncthreads();  // staging complete

            fx4 sAcc[4];
#pragma unroll
            for (int t = 0; t < 4; ++t) sAcc[t] = zero;
#pragma unroll
            for (int ks = 0; ks < 4; ++ks)
#pragma unroll
                for (int tn = 0; tn < 4; ++tn) {
                    int key = tn * 16 + l15;
                    bfx8 kf = *(const bfx8*)&Ks[key * 128 +
                                                (((ks * 4 + quad) ^ (key & 7)) * 8)];
                    sAcc[tn] = __builtin_amdgcn_mfma_f32_16x16x32_bf16(
                        qf[ks], kf, sAcc[tn], 0, 0, 0);
                }
            if (kt == qt) {  // causal mask, diagonal tile only
#pragma unroll
                for (int tn = 0; tn < 4; ++tn)
#pragma unroll
                    for (int r = 0; r < 4; ++r) {
                        int qrow = wave * 16 + quad * 4 + r;
                        int krow = tn * 16 + l15;
                        if (krow > qrow) sAcc[tn][r] = NEG_INF;
                    }
            }
            float alpha[4];
#pragma unroll
            for (int r = 0; r < 4; ++r) {
                float mx = fmaxf(fmaxf(sAcc[0][r], sAcc[1][r]),
                                 fmaxf(sAcc[2][r], sAcc[3][r]));
#pragma unroll
                for (int d = 1; d < 16; d <<= 1) mx = fmaxf(mx, __shfl_xor(mx, d));
                float mnew = fmaxf(mrow[r], mx);
                alpha[r] = exp2f(mrow[r] - mnew);
                mrow[r] = mnew;
                float rs = 0.f;
#pragma unroll
                for (int tn = 0; tn < 4; ++tn) {
                    float pv = exp2f(sAcc[tn][r] - mnew);
                    sAcc[tn][r] = pv;
                    rs += pv;
                }
                lrow[r] = lrow[r] * alpha[r] + rs;  // lane-partial, no shuffle
            }
#pragma unroll
            for (int tn = 0; tn < 4; ++tn)
#pragma unroll
                for (int r = 0; r < 4; ++r)
                    Ps[wave][(quad * 4 + r) * 72 + tn * 16 + l15] = f2bf(sAcc[tn][r]);
#pragma unroll
            for (int ht = 0; ht < 8; ++ht)
#pragma unroll
                for (int r = 0; r < 4; ++r) o[ht][r] *= alpha[r];
#pragma unroll
            for (int ks2 = 0; ks2 < 2; ++ks2) {
                bfx8 pf = *(const bfx8*)&Ps[wave][l15 * 72 + ks2 * 32 + quad * 8];
#pragma unroll
                for (int ht = 0; ht < 8; ++ht) {
                    int h = ht * 16 + l15;
                    bfx8 vf =
                        *(const bfx8*)&Vs[h * 64 + (((ks2 * 4 + quad) ^ (h & 7)) * 8)];
                    o[ht] = __builtin_amdgcn_mfma_f32_16x16x32_bf16(pf, vf, o[ht],
                                                                    0, 0, 0);
                }
            }
        }
        // epilogue: reduce lrow across the 16 lanes sharing each row, normalize
        float inv_l[4];
#pragma unroll
        for (int r = 0; r < 4; ++r) {
            float s = lrow[r];
#pragma unroll
            for (int d = 1; d < 16; d <<= 1) s += __shfl_xor(s, d);
            inv_l[r] = 1.f / s;
        }
#pragma unroll
        for (int ht = 0; ht < 8; ++ht)
#pragma unroll
            for (int r = 0; r < 4; ++r) {
                int t = qt * 64 + wave * 16 + quad * 4 + r;
                int col = n * 128 + ht * 16 + l15;
                attn[((size_t)(b * 1024 + t)) * 4096 + col] = f2bf(o[ht][r] * inv_l[r]);
            }
    }
}

extern "C" void kernel_launch(void* const* d_in, const int* in_sizes, int n_in,
                              void* d_out, int out_size, void* d_ws, size_t ws_size,
                              hipStream_t stream) {
    const float* x = (const float*)d_in[0];
    const int* pos = (const int*)d_in[1];
    const float* wq = (const float*)d_in[2];
    const float* wk = (const float*)d_in[3];
    const float* wv = (const float*)d_in[4];
    const float* wo = (const float*)d_in[5];
    const float* kc = (const float*)d_in[6];
    const float* vc = (const float*)d_in[7];
    const int* wi = (const int*)d_in[8];

    float* kc_out = (float*)d_out;   // (8, 4096, 128)
    float* vc_out = kc_out + 4194304;
    float* o_out = vc_out + 4194304; // (2, 1024, 4096)

    u16* wsp = (u16*)d_ws;
    u16* x_bf  = wsp;                // (2048, 4096)
    u16* wqkvT = x_bf + 8388608;     // (6144, 4096) heads x (H, D)
    u16* woT   = wqkvT + 25165824;   // (4096, 4096)
    u16* qkv   = woT + 16777216;     // (2048, 6144)
    u16* qbuf  = qkv + 12582912;     // (2, 32, 1024, 128)
    u16* kbuf  = qbuf + 8388608;     // (2, 8, 1024, 128)
    u16* vtb   = kbuf + 2097152;     // (2, 8, 128, 1024)
    u16* attn  = vtb + 2097152;      // (2048, 4096)

    prep<<<18432, 256, 0, stream>>>(x, wq, wk, wv, wo, kc, vc, x_bf, wqkvT, woT,
                                    kc_out);
    gemm_qkv<<<dim3(48, 16), 256, 0, stream>>>(x_bf, wqkvT, qkv, 2048, 6144, 4096);
    rope_tv<<<25088, 256, 0, stream>>>(qkv, pos, wi, qbuf, kbuf, kc_out, vc_out, vtb);
    flash_attn<<<dim3(8, 32, 2), 256, 0, stream>>>(qbuf, kbuf, vtb, attn);
    gemm_out<<<dim3(32, 16), 256, 0, stream>>>(attn, woT, o_out, 2048, 4096, 4096);
}